// Round 18
// baseline (739.624 us; speedup 1.0000x reference)
//
#include <hip/hip_runtime.h>

typedef unsigned short ushort_t;
typedef unsigned int u32;
typedef short bf16x8 __attribute__((ext_vector_type(8)));
typedef float f32x4 __attribute__((ext_vector_type(4)));
typedef float f32x16 __attribute__((ext_vector_type(16)));
typedef u32 u32x4 __attribute__((ext_vector_type(4)));

__device__ __forceinline__ ushort_t f2bf(float f) {
  u32 u = __builtin_bit_cast(u32, f);
  u += 0x7FFFu + ((u >> 16) & 1u);   // round-to-nearest-even
  return (ushort_t)(u >> 16);
}
__device__ __forceinline__ float bf2f(u32 bits16) {
  return __builtin_bit_cast(float, bits16 << 16);
}

// ---------------- fp32 -> bf16 convert (8 elems/thread) ----------------
__device__ __forceinline__ void cvt_body(const float* __restrict__ in,
                                         ushort_t* __restrict__ out, int i) {
  const float4 a = ((const float4*)in)[(size_t)i * 2];
  const float4 b = ((const float4*)in)[(size_t)i * 2 + 1];
  uint4 r;
  r.x = (u32)f2bf(a.x) | ((u32)f2bf(a.y) << 16);
  r.y = (u32)f2bf(a.z) | ((u32)f2bf(a.w) << 16);
  r.z = (u32)f2bf(b.x) | ((u32)f2bf(b.y) << 16);
  r.w = (u32)f2bf(b.z) | ((u32)f2bf(b.w) << 16);
  ((uint4*)out)[i] = r;
}

// Row-permuted convert for wq/wk ([evens|odds] within each 32-row block):
// puts each RoPE pair in ONE lane of the GEMM C-fragment -> shuffle-free
// epilogue. QK^T invariant (same head-dim permutation on Q and K).
__device__ __forceinline__ void cvt_perm_body(const float* __restrict__ in,
                                              ushort_t* __restrict__ out, int i) {
  const int row = i >> 9, k8 = i & 511;
  const int q = row & 31;
  const int lrow = (row & ~31) | ((q < 16) ? (2 * q) : (2 * (q - 16) + 1));
  const float4 a = ((const float4*)in)[(size_t)lrow * 1024 + k8 * 2];
  const float4 b = ((const float4*)in)[(size_t)lrow * 1024 + k8 * 2 + 1];
  uint4 r;
  r.x = (u32)f2bf(a.x) | ((u32)f2bf(a.y) << 16);
  r.y = (u32)f2bf(a.z) | ((u32)f2bf(a.w) << 16);
  r.z = (u32)f2bf(b.x) | ((u32)f2bf(b.y) << 16);
  r.w = (u32)f2bf(b.z) | ((u32)f2bf(b.w) << 16);
  ((uint4*)out)[(size_t)row * 512 + k8] = r;
}

// y=0: x (plain) + packed cos/sin table (first 512 blocks); y=1: wq (permuted).
__global__ __launch_bounds__(256)
void cvt2_kernel(const float* __restrict__ i0, ushort_t* __restrict__ o0,
                 const float* __restrict__ i1, ushort_t* __restrict__ o1,
                 const float* __restrict__ fcos, const float* __restrict__ fsin,
                 float2* __restrict__ cst) {
  const int i = blockIdx.x * 256 + threadIdx.x;
  if (blockIdx.y == 0) {
    if (blockIdx.x < 512) cst[i] = make_float2(fcos[i], fsin[i]);
    cvt_body(i0, o0, i);
  } else {
    cvt_perm_body(i1, o1, i);
  }
}

// ---------------- GEMM 256x256, BK=32, 3-slot LDS, counted vmcnt(4) ----------
// C[m][n] = sum_k A[m][k]*B[n][k] (B^T input). 512 thr = 8 waves (2M x 4N),
// per-wave 128x64 (acc 8x4 f32x4). 3 LDS slots x 16KB per tensor (96 KiB):
// stage tile t+2 -> slot (t+2)%3 at tile-t start, read slot t%3, ONE barrier
// per tile, vmcnt(4) at tile end — drains tile-(t+1)'s stages (issued a full
// tile ago -> free wait) while THIS tile's 4 stay in flight across the
// barrier (T4's real mechanism; 2-slot dbuf forces a full drain instead).
// Swizzle (64B rows): read chunk g^((lq>>1)&3) — 16 lanes -> 8 quad-bank
// groups x2 (2-way = free); inverse-applied to gload source. ROPE=1:
// shuffle-free RoPE epilogue (permuted weights, pair in-lane). CVT!=0:
// blocks >= 256 convert the next GEMM's weight (r17 keeper).
template <int F32OUT, int ROPE, int CVT>
__global__ __launch_bounds__(512, 2)
void gemm256(const ushort_t* __restrict__ A, const ushort_t* __restrict__ B,
             void* __restrict__ C, const float2* __restrict__ cst, float qsc,
             const float* __restrict__ csrc, ushort_t* __restrict__ cdst) {
  constexpr int KD = 4096, ND = 4096;
  __shared__ ushort_t sA[3][256 * 32];
  __shared__ ushort_t sB[3][256 * 32];
  const int tid = threadIdx.x;
  const int id = blockIdx.x;
  if (CVT && id >= 256) {   // fused convert path (blocks 256..767)
    const int cb_ = id - 256;
#pragma unroll 2
    for (int it = 0; it < 8; ++it) {
      const int i = it * 262144 + cb_ * 512 + tid;
      if (CVT == 1) cvt_perm_body(csrc, cdst, i);
      else cvt_body(csrc, cdst, i);
    }
    return;
  }
  const int lane = tid & 63, wave = tid >> 6;
  const int lq = lane & 15, g = lane >> 4;
  const int wm = wave >> 2, wn = wave & 3;
  const int swz = (id & 7) * 32 + (id >> 3);       // bijective XCD swizzle (256%8==0)
  const int bm = (swz >> 4) * 256;
  const int bn = (swz & 15) * 256;
  const int rsw = (g ^ ((lq >> 1) & 3)) * 8;       // read-side chunk swizzle

  f32x4 acc[8][4];
#pragma unroll
  for (int m = 0; m < 8; ++m)
#pragma unroll
    for (int n = 0; n < 4; ++n) acc[m][n] = (f32x4)0.f;

// stage one 256x32 tile of tensor G (K-tile t_, slot s_); 2 gload_lds/thread;
// LDS dest linear in j (wave-uniform base + lane*16B), source chunk
// pre-swizzled with the inverse of the read swizzle.
#define STG(sbuf, G, rowb, t_, s_)                                                   \
  {                                                                                  \
    _Pragma("unroll") for (int i_ = 0; i_ < 2; ++i_) {                               \
      const int j_ = i_ * 512 + wave * 64 + lane;                                    \
      const int r_ = j_ >> 2, cp_ = j_ & 3;                                          \
      const int tc_ = (t_) > 127 ? 127 : (t_);                                       \
      const ushort_t* src_ = (G) + (size_t)((rowb) + r_) * KD + tc_ * 32 +           \
                             ((cp_ ^ ((r_ >> 1) & 3)) * 8);                          \
      __builtin_amdgcn_global_load_lds(                                              \
          (const __attribute__((address_space(1))) u32*)src_,                        \
          (__attribute__((address_space(3))) u32*)&sbuf[s_][j_ * 8], 16, 0, 0);      \
    }                                                                                \
  }
#define RD_A(S_, mf_)                                                                 \
  (*(const bf16x8*)&sA[S_][(wm * 128 + (mf_) * 16 + lq) * 32 + rsw])
#define RD_B(S_, nf_)                                                                 \
  (*(const bf16x8*)&sB[S_][(wn * 64 + (nf_) * 16 + lq) * 32 + rsw])

  // ---- prologue: stage tiles 0,1 -> slots 0,1; drain tile0; rendezvous ----
  STG(sA, A, bm, 0, 0); STG(sB, B, bn, 0, 0);
  STG(sA, A, bm, 1, 1); STG(sB, B, bn, 1, 1);
  asm volatile("s_waitcnt vmcnt(4)" ::: "memory");
  __builtin_amdgcn_s_barrier();
  __builtin_amdgcn_sched_barrier(0);

  bf16x8 af[8], bfr[4];

// One K-tile: stage t+2 -> slot S2_; read slot S_ (8 A + 4 B ds_reads);
// 32 MFMA; vmcnt(4) (tile t+1's stages drained, THIS tile's stay in flight
// across the barrier); barrier.
#define TILE(S_, S2_, T_)                                                             \
  STG(sA, A, bm, (T_) + 2, S2_);                                                      \
  STG(sB, B, bn, (T_) + 2, S2_);                                                      \
  _Pragma("unroll") for (int mf = 0; mf < 8; ++mf) af[mf] = RD_A(S_, mf);             \
  _Pragma("unroll") for (int nf = 0; nf < 4; ++nf) bfr[nf] = RD_B(S_, nf);            \
  __builtin_amdgcn_s_setprio(1);                                                      \
  _Pragma("unroll") for (int mf = 0; mf < 8; ++mf)                                    \
    _Pragma("unroll") for (int nf = 0; nf < 4; ++nf)                                  \
      acc[mf][nf] = __builtin_amdgcn_mfma_f32_16x16x32_bf16(af[mf], bfr[nf],          \
                                                            acc[mf][nf], 0, 0, 0);   \
  __builtin_amdgcn_s_setprio(0);                                                      \
  asm volatile("s_waitcnt vmcnt(4)" ::: "memory");                                    \
  __builtin_amdgcn_s_barrier();                                                       \
  __builtin_amdgcn_sched_barrier(0);

  for (int t = 0; t < 126; t += 3) {
    TILE(0, 2, t)
    TILE(1, 0, t + 1)
    TILE(2, 1, t + 2)
  }
  TILE(0, 2, 126)
  TILE(1, 0, 127)
#undef TILE
#undef STG
#undef RD_A
#undef RD_B

  // ---- epilogue: C store (16x16 C/D: col=lq, row=g*4+reg) ----
  if (ROPE) {
#pragma unroll
    for (int mf = 0; mf < 8; ++mf) {
      const int grow = bm + wm * 128 + mf * 16 + g * 4;
#pragma unroll
      for (int r = 0; r < 4; ++r) {
        const int row = grow + r;
#pragma unroll
        for (int pr = 0; pr < 2; ++pr) {
          const int p = ((wn * 2 + pr) & 3) * 16 + lq;   // head-pair index
          const float2 cs = cst[(size_t)(row & 2047) * 64 + p];
          const float t0 = acc[mf][pr * 2][r];
          const float t1 = acc[mf][pr * 2 + 1][r];
          const int c0 = bn + wn * 64 + pr * 32 + lq;
          ((ushort_t*)C)[(size_t)row * ND + c0] =
              f2bf((t0 * cs.x - t1 * cs.y) * qsc);
          ((ushort_t*)C)[(size_t)row * ND + c0 + 16] =
              f2bf((t0 * cs.y + t1 * cs.x) * qsc);
        }
      }
    }
  } else {
#pragma unroll
    for (int mf = 0; mf < 8; ++mf) {
      const int grow = bm + wm * 128 + mf * 16 + g * 4;
#pragma unroll
      for (int r = 0; r < 4; ++r) {
        const int row = grow + r;
#pragma unroll
        for (int nf = 0; nf < 4; ++nf) {
          const int gcol = bn + wn * 64 + nf * 16 + lq;
          if (F32OUT)
            ((float*)C)[(size_t)row * ND + gcol] = acc[mf][nf][r];
          else
            ((ushort_t*)C)[(size_t)row * ND + gcol] = f2bf(acc[mf][nf][r]);
        }
      }
    }
  }
}

// ---------------- Flash attention, causal, 32x32 MFMA, folded-balance ----------------
// Blocks >= 512 convert wo (fp32->bf16) — co-resident with 33K-LDS attn blocks.
__global__ __launch_bounds__(256, 2)
void attn_kernel(const ushort_t* __restrict__ Q, const ushort_t* __restrict__ K,
                 const ushort_t* __restrict__ Vt, ushort_t* __restrict__ O,
                 const float* __restrict__ csrc, ushort_t* __restrict__ cdst) {
  __shared__ ushort_t sK[2][32 * 128];   // swizzled col16 ^= row&7
  __shared__ ushort_t sV[2][128 * 32];   // swizzled slot ^= (d>>1)&3
  __shared__ float sScr[4][32];

  const int bp = blockIdx.x;
  if (bp >= 512) {   // fused convert path (blocks 512..1023)
    const int cb_ = bp - 512;
#pragma unroll 2
    for (int it = 0; it < 16; ++it)
      cvt_body(csrc, cdst, it * 131072 + cb_ * 256 + threadIdx.x);
    return;
  }

  const int lane = threadIdx.x & 63, wave = threadIdx.x >> 6;
  const int lq = lane & 31, hi = lane >> 5;
  const int bh = bp >> 3, j = bp & 7;
  const int h = bh & 31, b = bh >> 5;
  const ushort_t* Kb_ = K + (size_t)(b * 2048) * 4096 + h * 128;
  const ushort_t* Vb_ = Vt + (size_t)(h * 128) * 4096 + b * 2048;

#define STAGE(buf, kt_)                                                              \
  {                                                                                  \
    const int kb_ = (kt_) * 32;                                                      \
    _Pragma("unroll")                                                                \
    for (int i_ = 0; i_ < 2; ++i_) {                                                 \
      const int c_ = wave + i_ * 4;                                                  \
      const int krow = c_ * 4 + (lane >> 4);                                         \
      const int kcol = (lane & 15) ^ (krow & 7);                                     \
      const ushort_t* ksrc = Kb_ + (size_t)(kb_ + krow) * 4096 + kcol * 8;           \
      __builtin_amdgcn_global_load_lds(                                              \
          (const __attribute__((address_space(1))) u32*)ksrc,                        \
          (__attribute__((address_space(3))) u32*)&sK[buf][c_ * 512 + lane * 8],     \
          16, 0, 0);                                                                 \
      const int sst = c_ * 64 + lane;                                                \
      const int dv = sst >> 2;                                                       \
      const int gl = (sst & 3) ^ ((sst >> 3) & 3);                                   \
      const ushort_t* vsrc = Vb_ + (size_t)dv * 4096 + kb_ + gl * 8;                 \
      __builtin_amdgcn_global_load_lds(                                              \
          (const __attribute__((address_space(1))) u32*)vsrc,                        \
          (__attribute__((address_space(3))) u32*)&sV[buf][sst * 8], 16, 0, 0);      \
    }                                                                                \
  }

  for (int ph = 0; ph < 2; ++ph) {
    const int qj = ph ? (15 - j) : j;
    const int qbase = qj * 128 + wave * 32;
    const int ntw = qj * 4 + wave + 1;   // tiles this wave computes
    const int ntmax = qj * 4 + 4;        // tiles the block stages

    bf16x8 aq[8];
    const ushort_t* qrow = Q + (size_t)(b * 2048 + qbase + lq) * 4096 + h * 128 + hi * 8;
#pragma unroll
    for (int kf = 0; kf < 8; ++kf) aq[kf] = *(const bf16x8*)(qrow + kf * 16);

    f32x16 o[4];
#pragma unroll
    for (int dt = 0; dt < 4; ++dt) o[dt] = (f32x16)0.f;
    float m_run = -1e30f, l_run = 0.f;

    int cur = 0;
    STAGE(0, 0);
    __syncthreads();

    for (int kt = 0; kt < ntmax; ++kt) {
      if (kt + 1 < ntmax) STAGE(cur ^ 1, kt + 1);
      if (kt < ntw) {
        const int kb = kt * 32;
        f32x16 st = (f32x16)0.f;
#pragma unroll
        for (int kf = 0; kf < 8; ++kf) {
          const bf16x8 kfrag =
              *(const bf16x8*)&sK[cur][lq * 128 + (((kf * 2 + hi) ^ (lq & 7)) * 8)];
          st = __builtin_amdgcn_mfma_f32_32x32x16_bf16(kfrag, aq[kf], st, 0, 0, 0);
        }
        if (kt == ntw - 1) {
          const int q = qbase + lq;
#pragma unroll
          for (int r = 0; r < 16; ++r) {
            const int key = kb + (r & 3) + 8 * (r >> 2) + 4 * hi;
            if (key > q) st[r] = -1e30f;
          }
        }
        float tm = st[0];
#pragma unroll
        for (int r = 1; r < 16; ++r) tm = fmaxf(tm, st[r]);
        tm = fmaxf(tm, __shfl_xor(tm, 32));
        if (!__all(tm <= m_run + 8.f)) {   // T13 defer-max
          const float mnew = fmaxf(m_run, tm);
          const float corr = __expf(m_run - mnew);
          m_run = mnew;
          l_run *= corr;
          if (hi == 0) sScr[wave][lq] = corr;
          float fr[16];
#pragma unroll
          for (int r = 0; r < 16; ++r)
            fr[r] = sScr[wave][(r & 3) + 8 * (r >> 2) + 4 * hi];
#pragma unroll
          for (int dt = 0; dt < 4; ++dt)
#pragma unroll
            for (int r = 0; r < 16; ++r) o[dt][r] *= fr[r];
        }
        float rs = 0.f;
#pragma unroll
        for (int r = 0; r < 16; ++r) { st[r] = __expf(st[r] - m_run); rs += st[r]; }
        rs += __shfl_xor(rs, 32);
        l_run += rs;
        u32 A_, B_, C_, D_, E_, F_, G_, H_;
#define CVTPK(d_, l_, h_) \
  asm("v_cvt_pk_bf16_f32 %0, %1, %2" : "=v"(d_) : "v"(l_), "v"(h_))
        CVTPK(A_, st[0], st[1]);  CVTPK(B_, st[4], st[5]);
        CVTPK(C_, st[2], st[3]);  CVTPK(D_, st[6], st[7]);
        CVTPK(E_, st[8], st[9]);  CVTPK(F_, st[12], st[13]);
        CVTPK(G_, st[10], st[11]); CVTPK(H_, st[14], st[15]);
#undef CVTPK
        asm volatile("v_permlane32_swap_b32 %0, %1" : "+v"(A_), "+v"(B_));
        asm volatile("v_permlane32_swap_b32 %0, %1" : "+v"(C_), "+v"(D_));
        asm volatile("v_permlane32_swap_b32 %0, %1" : "+v"(E_), "+v"(F_));
        asm volatile("v_permlane32_swap_b32 %0, %1" : "+v"(G_), "+v"(H_));
        const bf16x8 pa0 = __builtin_bit_cast(bf16x8, (u32x4){A_, C_, B_, D_});
        const bf16x8 pa1 = __builtin_bit_cast(bf16x8, (u32x4){E_, G_, F_, H_});
#pragma unroll
        for (int dt = 0; dt < 4; ++dt) {
          const int d0 = dt * 32 + lq;
          const int s0 = 4 * d0 + ((hi + 0) ^ ((d0 >> 1) & 3));
          const int s1 = 4 * d0 + ((hi + 2) ^ ((d0 >> 1) & 3));
          const bf16x8 vf0 = *(const bf16x8*)&sV[cur][s0 * 8];
          const bf16x8 vf1 = *(const bf16x8*)&sV[cur][s1 * 8];
          o[dt] = __builtin_amdgcn_mfma_f32_32x32x16_bf16(pa0, vf0, o[dt], 0, 0, 0);
          o[dt] = __builtin_amdgcn_mfma_f32_32x32x16_bf16(pa1, vf1, o[dt], 0, 0, 0);
        }
      }
      __syncthreads();
      cur ^= 1;
    }

    if (hi == 0) sScr[wave][lq] = 1.f / l_run;
    __syncthreads();
    const size_t obase = (size_t)(b * 2048 + qbase) * 4096 + h * 128;
#pragma unroll
    for (int r = 0; r < 16; ++r) {
      const int qr = (r & 3) + 8 * (r >> 2) + 4 * hi;
      const float f = sScr[wave][qr];
#pragma unroll
      for (int dt = 0; dt < 4; ++dt)
        O[obase + (size_t)qr * 4096 + dt * 32 + lq] = f2bf(o[dt][r] * f);
    }
    __syncthreads();
  }
#undef STAGE
}

// ---------------- host ----------------
extern "C" void kernel_launch(void* const* d_in, const int* in_sizes, int n_in,
                              void* d_out, int out_size, void* d_ws, size_t ws_size,
                              hipStream_t stream) {
  const float* x = (const float*)d_in[0];
  const float* fcos = (const float*)d_in[2];
  const float* fsin = (const float*)d_in[3];
  const float* wq = (const float*)d_in[5];
  const float* wk = (const float*)d_in[6];
  const float* wv = (const float*)d_in[7];
  const float* wo = (const float*)d_in[8];
  float* out = (float*)d_out;
  char* ws = (char*)d_ws;
  const size_t MB32 = 33554432;  // 4096*4096*2 bytes
  ushort_t* xb = (ushort_t*)(ws);            // x bf16; later reused as attn-out
  ushort_t* wb = (ushort_t*)(ws + MB32);     // wq -> wv -> wo (bf16)
  ushort_t* Qb = (ushort_t*)(ws + 2 * MB32);
  ushort_t* Kb = (ushort_t*)(ws + 3 * MB32);
  ushort_t* Vt = (ushort_t*)(ws + 4 * MB32); // wk bf16 parked here, then V^T
  ushort_t* Ob = xb;
  float2* cst = (float2*)d_out;  // packed cos/sin table; overwritten by final GEMM

  const dim3 cb(256);
  const dim3 gb(512);
  const float QSC = 0.08838834764831845f;

  // 1. x (plain) + wq (permuted) + cos/sin table
  hipLaunchKernelGGL(cvt2_kernel, dim3(8192, 2), cb, 0, stream, x, xb, wq, wb,
                     fcos, fsin, cst);
  // 2. Q projection (RoPE+scale fused) + fused convert wk -> Vt (permuted)
  hipLaunchKernelGGL((gemm256<0, 1, 1>), dim3(768), gb, 0, stream, xb, wb,
                     (void*)Qb, cst, QSC, wk, Vt);
  // 3. K projection (RoPE fused, B = wk in Vt) + fused convert wv -> wb
  hipLaunchKernelGGL((gemm256<0, 1, 2>), dim3(768), gb, 0, stream, xb, Vt,
                     (void*)Kb, cst, 1.f, wv, wb);
  // 4. V^T = Wv @ x^T (overwrites Vt)
  hipLaunchKernelGGL((gemm256<0, 0, 0>), dim3(256), gb, 0, stream, wb, xb,
                     (void*)Vt, cst, 1.f, nullptr, nullptr);
  // 5. attention + fused convert wo -> wb (co-resident, true overlap)
  hipLaunchKernelGGL(attn_kernel, dim3(1024), cb, 0, stream, Qb, Kb, Vt, Ob, wo, wb);
  // 6. output projection (f32 out; overwrites the table region of d_out)
  hipLaunchKernelGGL((gemm256<1, 0, 0>), dim3(256), gb, 0, stream, Ob, wb,
                     (void*)out, cst, 1.f, nullptr, nullptr);
}

// Round 19
// 657.441 us; speedup vs baseline: 1.1250x; 1.1250x over previous
//
#include <hip/hip_runtime.h>

typedef unsigned short ushort_t;
typedef unsigned int u32;
typedef short bf16x8 __attribute__((ext_vector_type(8)));
typedef float f32x4 __attribute__((ext_vector_type(4)));
typedef float f32x16 __attribute__((ext_vector_type(16)));
typedef u32 u32x4 __attribute__((ext_vector_type(4)));

__device__ __forceinline__ ushort_t f2bf(float f) {
  u32 u = __builtin_bit_cast(u32, f);
  u += 0x7FFFu + ((u >> 16) & 1u);   // round-to-nearest-even
  return (ushort_t)(u >> 16);
}
__device__ __forceinline__ float bf2f(u32 bits16) {
  return __builtin_bit_cast(float, bits16 << 16);
}

// ---------------- fp32 -> bf16 convert (8 elems/thread) ----------------
__device__ __forceinline__ void cvt_body(const float* __restrict__ in,
                                         ushort_t* __restrict__ out, int i) {
  const float4 a = ((const float4*)in)[(size_t)i * 2];
  const float4 b = ((const float4*)in)[(size_t)i * 2 + 1];
  uint4 r;
  r.x = (u32)f2bf(a.x) | ((u32)f2bf(a.y) << 16);
  r.y = (u32)f2bf(a.z) | ((u32)f2bf(a.w) << 16);
  r.z = (u32)f2bf(b.x) | ((u32)f2bf(b.y) << 16);
  r.w = (u32)f2bf(b.z) | ((u32)f2bf(b.w) << 16);
  ((uint4*)out)[i] = r;
}

// Row-permuted convert for wq/wk ([evens|odds] within each 32-row block):
// puts each RoPE pair in ONE lane of the GEMM C-fragment -> shuffle-free
// epilogue. QK^T invariant (same head-dim permutation on Q and K).
__device__ __forceinline__ void cvt_perm_body(const float* __restrict__ in,
                                              ushort_t* __restrict__ out, int i) {
  const int row = i >> 9, k8 = i & 511;
  const int q = row & 31;
  const int lrow = (row & ~31) | ((q < 16) ? (2 * q) : (2 * (q - 16) + 1));
  const float4 a = ((const float4*)in)[(size_t)lrow * 1024 + k8 * 2];
  const float4 b = ((const float4*)in)[(size_t)lrow * 1024 + k8 * 2 + 1];
  uint4 r;
  r.x = (u32)f2bf(a.x) | ((u32)f2bf(a.y) << 16);
  r.y = (u32)f2bf(a.z) | ((u32)f2bf(a.w) << 16);
  r.z = (u32)f2bf(b.x) | ((u32)f2bf(b.y) << 16);
  r.w = (u32)f2bf(b.z) | ((u32)f2bf(b.w) << 16);
  ((uint4*)out)[(size_t)row * 512 + k8] = r;
}

// y=0: x (plain) + packed cos/sin table (first 512 blocks); y=1: wq (permuted).
__global__ __launch_bounds__(256)
void cvt2_kernel(const float* __restrict__ i0, ushort_t* __restrict__ o0,
                 const float* __restrict__ i1, ushort_t* __restrict__ o1,
                 const float* __restrict__ fcos, const float* __restrict__ fsin,
                 float2* __restrict__ cst) {
  const int i = blockIdx.x * 256 + threadIdx.x;
  if (blockIdx.y == 0) {
    if (blockIdx.x < 512) cst[i] = make_float2(fcos[i], fsin[i]);
    cvt_body(i0, o0, i);
  } else {
    cvt_perm_body(i1, o1, i);
  }
}

// ---------------- GEMM 256x256, 16x16x32, 1 barrier/K-tile (r15 structure) --------
// C[m][n] = sum_k A[m][k]*B[n][k] (B^T input). 512 thr = 8 waves (2M x 4N).
// LDS 128 KiB. T2 chunk^=(row&7) swizzle. ROPE=1: shuffle-free RoPE epilogue.
// CVT!=0: blocks >= 256 convert the NEXT GEMM's weight (fp32->bf16; CVT==1
// row-permuted) — they queue behind the GEMM blocks (same 128K LDS footprint)
// and run in the straggler tail: saves a dispatch ramp and leaves the weight
// L2-hot for the next GEMM. Top-level wave-uniform branch (no acc-spill).
template <int F32OUT, int ROPE, int CVT>
__global__ __launch_bounds__(512, 2)
void gemm256(const ushort_t* __restrict__ A, const ushort_t* __restrict__ B,
             void* __restrict__ C, const float2* __restrict__ cst, float qsc,
             const float* __restrict__ csrc, ushort_t* __restrict__ cdst) {
  constexpr int KD = 4096, ND = 4096;
  __shared__ ushort_t sA[2][2][128 * 64];
  __shared__ ushort_t sB[2][2][128 * 64];
  const int tid = threadIdx.x;
  const int id = blockIdx.x;
  if (CVT && id >= 256) {   // fused convert path (blocks 256..767)
    const int cb_ = id - 256;
#pragma unroll 2
    for (int it = 0; it < 8; ++it) {
      const int i = it * 262144 + cb_ * 512 + tid;
      if (CVT == 1) cvt_perm_body(csrc, cdst, i);
      else cvt_body(csrc, cdst, i);
    }
    return;
  }
  const int lane = tid & 63, wave = tid >> 6;
  const int lq = lane & 15, g = lane >> 4;
  const int wm = wave >> 2, wn = wave & 3;
  const int swz = (id & 7) * 32 + (id >> 3);       // bijective XCD swizzle (256%8==0)
  const int bm = (swz >> 4) * 256;
  const int bn = (swz & 15) * 256;
  const int csw = ((lane & 7) ^ (lane >> 3)) * 8;  // inverse-swizzled source chunk
  const int srow = lane >> 3;

  f32x4 acc[8][4];
#pragma unroll
  for (int m = 0; m < 8; ++m)
#pragma unroll
    for (int n = 0; n < 4; ++n) acc[m][n] = (f32x4)0.f;

#define STG(sbuf, G, rowb, t_, s_, h_)                                               \
  {                                                                                  \
    _Pragma("unroll") for (int i_ = 0; i_ < 2; ++i_) {                               \
      const int r0_ = wave * 16 + i_ * 8;                                            \
      const int tc_ = (t_) > 63 ? 63 : (t_);                                         \
      const ushort_t* src_ =                                                         \
          (G) + (size_t)((rowb) + (h_) * 128 + r0_ + srow) * KD + tc_ * 64 + csw;    \
      __builtin_amdgcn_global_load_lds(                                              \
          (const __attribute__((address_space(1))) u32*)src_,                        \
          (__attribute__((address_space(3))) u32*)&sbuf[s_][h_][r0_ * 64 + lane * 8],\
          16, 0, 0);                                                                 \
    }                                                                                \
  }
#define RD_A(S_, H_, mf_, kk_)                                                        \
  (*(const bf16x8*)&sA[S_][H_][(wm * 64 + (mf_) * 16 + lq) * 64 +                     \
                               ((((kk_) * 4 + g) ^ (lq & 7)) * 8)])
#define RD_B(S_, H_, nf_, kk_)                                                        \
  (*(const bf16x8*)&sB[S_][H_][(wn * 32 + (nf_) * 16 + lq) * 64 +                     \
                               ((((kk_) * 4 + g) ^ (lq & 7)) * 8)])
#define MM2(MB, B0R, B1R)                                                             \
  _Pragma("unroll") for (int mf = 0; mf < 4; ++mf)                                    \
    _Pragma("unroll") for (int nf = 0; nf < 2; ++nf)                                  \
      _Pragma("unroll") for (int kk = 0; kk < 2; ++kk) {                              \
        acc[(MB) + mf][nf] = __builtin_amdgcn_mfma_f32_16x16x32_bf16(                 \
            af[mf][kk], B0R[nf][kk], acc[(MB) + mf][nf], 0, 0, 0);                    \
        acc[(MB) + mf][2 + nf] = __builtin_amdgcn_mfma_f32_16x16x32_bf16(             \
            af[mf][kk], B1R[nf][kk], acc[(MB) + mf][2 + nf], 0, 0, 0);                \
      }

  // ---- prologue: stage tile0 -> slot0, drain, rendezvous ----
  STG(sA, A, bm, 0, 0, 0); STG(sA, A, bm, 0, 0, 1);
  STG(sB, B, bn, 0, 0, 0); STG(sB, B, bn, 0, 0, 1);
  asm volatile("s_waitcnt vmcnt(0)" ::: "memory");
  __builtin_amdgcn_s_barrier();
  __builtin_amdgcn_sched_barrier(0);

  bf16x8 af[4][2], b0[2][2], b1[2][2];

#define TILE(S_, T_)                                                                  \
  STG(sA, A, bm, (T_) + 1, (S_) ^ 1, 0);                                              \
  STG(sA, A, bm, (T_) + 1, (S_) ^ 1, 1);                                              \
  STG(sB, B, bn, (T_) + 1, (S_) ^ 1, 0);                                              \
  STG(sB, B, bn, (T_) + 1, (S_) ^ 1, 1);                                              \
  _Pragma("unroll") for (int mf = 0; mf < 4; ++mf)                                    \
    _Pragma("unroll") for (int kk = 0; kk < 2; ++kk)                                  \
      af[mf][kk] = RD_A(S_, 0, mf, kk);                                               \
  _Pragma("unroll") for (int nf = 0; nf < 2; ++nf)                                    \
    _Pragma("unroll") for (int kk = 0; kk < 2; ++kk) {                                \
      b0[nf][kk] = RD_B(S_, 0, nf, kk);                                               \
      b1[nf][kk] = RD_B(S_, 1, nf, kk);                                               \
    }                                                                                 \
  __builtin_amdgcn_s_setprio(1);                                                      \
  MM2(0, b0, b1);                                                                     \
  __builtin_amdgcn_s_setprio(0);                                                      \
  _Pragma("unroll") for (int mf = 0; mf < 4; ++mf)                                    \
    _Pragma("unroll") for (int kk = 0; kk < 2; ++kk)                                  \
      af[mf][kk] = RD_A(S_, 1, mf, kk);                                               \
  __builtin_amdgcn_s_setprio(1);                                                      \
  MM2(4, b0, b1);                                                                     \
  __builtin_amdgcn_s_setprio(0);                                                      \
  asm volatile("s_waitcnt vmcnt(0)" ::: "memory");                                    \
  __builtin_amdgcn_s_barrier();                                                       \
  __builtin_amdgcn_sched_barrier(0);

  for (int t = 0; t < 64; t += 2) {
    TILE(0, t)
    TILE(1, t + 1)
  }
#undef TILE
#undef STG
#undef RD_A
#undef RD_B
#undef MM2

  // ---- epilogue: C store (C/D layout col=lane&15, row=(lane>>4)*4+reg) ----
  if (ROPE) {
    const int p = wn * 16 + lq;   // pair index within head — thread-constant
#pragma unroll
    for (int m = 0; m < 8; ++m) {
      const int grow = bm + (m >> 2) * 128 + wm * 64 + (m & 3) * 16 + g * 4;
#pragma unroll
      for (int r = 0; r < 4; ++r) {
        const int row = grow + r;
        const float2 cs = cst[(size_t)(row & 2047) * 64 + p];
#pragma unroll
        for (int pr = 0; pr < 2; ++pr) {
          const float t0 = acc[m][pr * 2][r];
          const float t1 = acc[m][pr * 2 + 1][r];
          const int c0 = bn + pr * 128 + wn * 32 + lq;
          ((ushort_t*)C)[(size_t)row * ND + c0] =
              f2bf((t0 * cs.x - t1 * cs.y) * qsc);
          ((ushort_t*)C)[(size_t)row * ND + c0 + 16] =
              f2bf((t0 * cs.y + t1 * cs.x) * qsc);
        }
      }
    }
  } else {
#pragma unroll
    for (int m = 0; m < 8; ++m) {
      const int grow = bm + (m >> 2) * 128 + wm * 64 + (m & 3) * 16 + g * 4;
#pragma unroll
      for (int r = 0; r < 4; ++r) {
        const int row = grow + r;
#pragma unroll
        for (int n = 0; n < 4; ++n) {
          const int gcol = bn + (n >> 1) * 128 + wn * 32 + (n & 1) * 16 + lq;
          if (F32OUT)
            ((float*)C)[(size_t)row * ND + gcol] = acc[m][n][r];
          else
            ((ushort_t*)C)[(size_t)row * ND + gcol] = f2bf(acc[m][n][r]);
        }
      }
    }
  }
}

// ---------------- Flash attention, causal, 32x32 MFMA, folded-balance ----------------
// Blocks >= 512 convert wo (fp32->bf16) — 33K LDS attn blocks + cvt blocks
// co-reside, so the convert truly overlaps the attention compute.
__global__ __launch_bounds__(256, 2)
void attn_kernel(const ushort_t* __restrict__ Q, const ushort_t* __restrict__ K,
                 const ushort_t* __restrict__ Vt, ushort_t* __restrict__ O,
                 const float* __restrict__ csrc, ushort_t* __restrict__ cdst) {
  __shared__ ushort_t sK[2][32 * 128];   // swizzled col16 ^= row&7
  __shared__ ushort_t sV[2][128 * 32];   // swizzled slot ^= (d>>1)&3
  __shared__ float sScr[4][32];

  const int bp = blockIdx.x;
  if (bp >= 512) {   // fused convert path (blocks 512..1023)
    const int cb_ = bp - 512;
#pragma unroll 2
    for (int it = 0; it < 16; ++it)
      cvt_body(csrc, cdst, it * 131072 + cb_ * 256 + threadIdx.x);
    return;
  }

  const int lane = threadIdx.x & 63, wave = threadIdx.x >> 6;
  const int lq = lane & 31, hi = lane >> 5;
  const int bh = bp >> 3, j = bp & 7;
  const int h = bh & 31, b = bh >> 5;
  const ushort_t* Kb_ = K + (size_t)(b * 2048) * 4096 + h * 128;
  const ushort_t* Vb_ = Vt + (size_t)(h * 128) * 4096 + b * 2048;

#define STAGE(buf, kt_)                                                              \
  {                                                                                  \
    const int kb_ = (kt_) * 32;                                                      \
    _Pragma("unroll")                                                                \
    for (int i_ = 0; i_ < 2; ++i_) {                                                 \
      const int c_ = wave + i_ * 4;                                                  \
      const int krow = c_ * 4 + (lane >> 4);                                         \
      const int kcol = (lane & 15) ^ (krow & 7);                                     \
      const ushort_t* ksrc = Kb_ + (size_t)(kb_ + krow) * 4096 + kcol * 8;           \
      __builtin_amdgcn_global_load_lds(                                              \
          (const __attribute__((address_space(1))) u32*)ksrc,                        \
          (__attribute__((address_space(3))) u32*)&sK[buf][c_ * 512 + lane * 8],     \
          16, 0, 0);                                                                 \
      const int sst = c_ * 64 + lane;                                                \
      const int dv = sst >> 2;                                                       \
      const int gl = (sst & 3) ^ ((sst >> 3) & 3);                                   \
      const ushort_t* vsrc = Vb_ + (size_t)dv * 4096 + kb_ + gl * 8;                 \
      __builtin_amdgcn_global_load_lds(                                              \
          (const __attribute__((address_space(1))) u32*)vsrc,                        \
          (__attribute__((address_space(3))) u32*)&sV[buf][sst * 8], 16, 0, 0);      \
    }                                                                                \
  }

  for (int ph = 0; ph < 2; ++ph) {
    const int qj = ph ? (15 - j) : j;
    const int qbase = qj * 128 + wave * 32;
    const int ntw = qj * 4 + wave + 1;   // tiles this wave computes
    const int ntmax = qj * 4 + 4;        // tiles the block stages

    bf16x8 aq[8];
    const ushort_t* qrow = Q + (size_t)(b * 2048 + qbase + lq) * 4096 + h * 128 + hi * 8;
#pragma unroll
    for (int kf = 0; kf < 8; ++kf) aq[kf] = *(const bf16x8*)(qrow + kf * 16);

    f32x16 o[4];
#pragma unroll
    for (int dt = 0; dt < 4; ++dt) o[dt] = (f32x16)0.f;
    float m_run = -1e30f, l_run = 0.f;

    int cur = 0;
    STAGE(0, 0);
    __syncthreads();

    for (int kt = 0; kt < ntmax; ++kt) {
      if (kt + 1 < ntmax) STAGE(cur ^ 1, kt + 1);
      if (kt < ntw) {
        const int kb = kt * 32;
        f32x16 st = (f32x16)0.f;
#pragma unroll
        for (int kf = 0; kf < 8; ++kf) {
          const bf16x8 kfrag =
              *(const bf16x8*)&sK[cur][lq * 128 + (((kf * 2 + hi) ^ (lq & 7)) * 8)];
          st = __builtin_amdgcn_mfma_f32_32x32x16_bf16(kfrag, aq[kf], st, 0, 0, 0);
        }
        if (kt == ntw - 1) {
          const int q = qbase + lq;
#pragma unroll
          for (int r = 0; r < 16; ++r) {
            const int key = kb + (r & 3) + 8 * (r >> 2) + 4 * hi;
            if (key > q) st[r] = -1e30f;
          }
        }
        float tm = st[0];
#pragma unroll
        for (int r = 1; r < 16; ++r) tm = fmaxf(tm, st[r]);
        tm = fmaxf(tm, __shfl_xor(tm, 32));
        if (!__all(tm <= m_run + 8.f)) {   // T13 defer-max
          const float mnew = fmaxf(m_run, tm);
          const float corr = __expf(m_run - mnew);
          m_run = mnew;
          l_run *= corr;
          if (hi == 0) sScr[wave][lq] = corr;
          float fr[16];
#pragma unroll
          for (int r = 0; r < 16; ++r)
            fr[r] = sScr[wave][(r & 3) + 8 * (r >> 2) + 4 * hi];
#pragma unroll
          for (int dt = 0; dt < 4; ++dt)
#pragma unroll
            for (int r = 0; r < 16; ++r) o[dt][r] *= fr[r];
        }
        float rs = 0.f;
#pragma unroll
        for (int r = 0; r < 16; ++r) { st[r] = __expf(st[r] - m_run); rs += st[r]; }
        rs += __shfl_xor(rs, 32);
        l_run += rs;
        u32 A_, B_, C_, D_, E_, F_, G_, H_;
#define CVTPK(d_, l_, h_) \
  asm("v_cvt_pk_bf16_f32 %0, %1, %2" : "=v"(d_) : "v"(l_), "v"(h_))
        CVTPK(A_, st[0], st[1]);  CVTPK(B_, st[4], st[5]);
        CVTPK(C_, st[2], st[3]);  CVTPK(D_, st[6], st[7]);
        CVTPK(E_, st[8], st[9]);  CVTPK(F_, st[12], st[13]);
        CVTPK(G_, st[10], st[11]); CVTPK(H_, st[14], st[15]);
#undef CVTPK
        asm volatile("v_permlane32_swap_b32 %0, %1" : "+v"(A_), "+v"(B_));
        asm volatile("v_permlane32_swap_b32 %0, %1" : "+v"(C_), "+v"(D_));
        asm volatile("v_permlane32_swap_b32 %0, %1" : "+v"(E_), "+v"(F_));
        asm volatile("v_permlane32_swap_b32 %0, %1" : "+v"(G_), "+v"(H_));
        const bf16x8 pa0 = __builtin_bit_cast(bf16x8, (u32x4){A_, C_, B_, D_});
        const bf16x8 pa1 = __builtin_bit_cast(bf16x8, (u32x4){E_, G_, F_, H_});
#pragma unroll
        for (int dt = 0; dt < 4; ++dt) {
          const int d0 = dt * 32 + lq;
          const int s0 = 4 * d0 + ((hi + 0) ^ ((d0 >> 1) & 3));
          const int s1 = 4 * d0 + ((hi + 2) ^ ((d0 >> 1) & 3));
          const bf16x8 vf0 = *(const bf16x8*)&sV[cur][s0 * 8];
          const bf16x8 vf1 = *(const bf16x8*)&sV[cur][s1 * 8];
          o[dt] = __builtin_amdgcn_mfma_f32_32x32x16_bf16(pa0, vf0, o[dt], 0, 0, 0);
          o[dt] = __builtin_amdgcn_mfma_f32_32x32x16_bf16(pa1, vf1, o[dt], 0, 0, 0);
        }
      }
      __syncthreads();
      cur ^= 1;
    }

    if (hi == 0) sScr[wave][lq] = 1.f / l_run;
    __syncthreads();
    const size_t obase = (size_t)(b * 2048 + qbase) * 4096 + h * 128;
#pragma unroll
    for (int r = 0; r < 16; ++r) {
      const int qr = (r & 3) + 8 * (r >> 2) + 4 * hi;
      const float f = sScr[wave][qr];
#pragma unroll
      for (int dt = 0; dt < 4; ++dt)
        O[obase + (size_t)qr * 4096 + dt * 32 + lq] = f2bf(o[dt][r] * f);
    }
    __syncthreads();
  }
#undef STAGE
}

// ---------------- host ----------------
extern "C" void kernel_launch(void* const* d_in, const int* in_sizes, int n_in,
                              void* d_out, int out_size, void* d_ws, size_t ws_size,
                              hipStream_t stream) {
  const float* x = (const float*)d_in[0];
  const float* fcos = (const float*)d_in[2];
  const float* fsin = (const float*)d_in[3];
  const float* wq = (const float*)d_in[5];
  const float* wk = (const float*)d_in[6];
  const float* wv = (const float*)d_in[7];
  const float* wo = (const float*)d_in[8];
  float* out = (float*)d_out;
  char* ws = (char*)d_ws;
  const size_t MB32 = 33554432;  // 4096*4096*2 bytes
  ushort_t* xb = (ushort_t*)(ws);            // x bf16; later reused as attn-out
  ushort_t* wb = (ushort_t*)(ws + MB32);     // wq -> wv -> wo (bf16)
  ushort_t* Qb = (ushort_t*)(ws + 2 * MB32);
  ushort_t* Kb = (ushort_t*)(ws + 3 * MB32);
  ushort_t* Vt = (ushort_t*)(ws + 4 * MB32); // wk bf16 parked here, then V^T
  ushort_t* Ob = xb;
  float2* cst = (float2*)d_out;  // packed cos/sin table; overwritten by final GEMM

  const dim3 cb(256);
  const dim3 gb(512);
  const float QSC = 0.08838834764831845f;

  // 6 dispatches: weight converts ride inside adjacent dispatches.
  // 1. x (plain) + wq (permuted) + cos/sin table
  hipLaunchKernelGGL(cvt2_kernel, dim3(8192, 2), cb, 0, stream, x, xb, wq, wb,
                     fcos, fsin, cst);
  // 2. Q projection (RoPE+scale fused) + fused convert wk -> Vt (permuted)
  hipLaunchKernelGGL((gemm256<0, 1, 1>), dim3(768), gb, 0, stream, xb, wb,
                     (void*)Qb, cst, QSC, wk, Vt);
  // 3. K projection (RoPE fused, B = wk in Vt) + fused convert wv -> wb
  hipLaunchKernelGGL((gemm256<0, 1, 2>), dim3(768), gb, 0, stream, xb, Vt,
                     (void*)Kb, cst, 1.f, wv, wb);
  // 4. V^T = Wv @ x^T (overwrites Vt)
  hipLaunchKernelGGL((gemm256<0, 0, 0>), dim3(256), gb, 0, stream, wb, xb,
                     (void*)Vt, cst, 1.f, nullptr, nullptr);
  // 5. attention + fused convert wo -> wb (co-resident, true overlap)
  hipLaunchKernelGGL(attn_kernel, dim3(1024), cb, 0, stream, Qb, Kb, Vt, Ob, wo, wb);
  // 6. output projection (f32 out; overwrites the table region of d_out)
  hipLaunchKernelGGL((gemm256<1, 0, 0>), dim3(256), gb, 0, stream, Ob, wb,
                     (void*)out, cst, 1.f, nullptr, nullptr);
}